// Round 1
// baseline (2289.978 us; speedup 1.0000x reference)
//
#include <hip/hip_runtime.h>

// ---------------------------------------------------------------------------
// LigerLMHeadJSD: fused linear + beta-skew JSD (beta=0.5, T=1.0)
//   BT=2048, H=4096 (teacher) / 2048 (student), V=32000
// Pipeline: fp32->bf16 convert; 2x bf16 MFMA GEMM (m97 128^2 structure,
// global_load_lds staging); per-token LSE; per-token JSD reduce; finalize.
// ---------------------------------------------------------------------------

typedef __attribute__((ext_vector_type(8))) short bf16x8;
typedef __attribute__((ext_vector_type(4))) float f32x4;
typedef __attribute__((ext_vector_type(8))) unsigned short ushort8;
typedef __attribute__((ext_vector_type(4))) float float4v;
typedef __attribute__((ext_vector_type(4))) unsigned short ushort4v;

#define NTOK 2048
#define VOC  32000

__device__ __forceinline__ float bf2f(unsigned short u) {
  union { unsigned int i; float f; } v; v.i = ((unsigned int)u) << 16; return v.f;
}
__device__ __forceinline__ unsigned short f2bf(float f) {
  union { float f; unsigned int u; } v; v.f = f;
  unsigned int r = v.u + 0x7FFFu + ((v.u >> 16) & 1u);   // round-to-nearest-even
  return (unsigned short)(r >> 16);
}

// ---------------- fp32 -> bf16 convert (vectorized) ----------------
__global__ __launch_bounds__(256) void cvt_f32_bf16(const float* __restrict__ in,
                                                    unsigned short* __restrict__ out,
                                                    long n4) {
  long i = (long)blockIdx.x * blockDim.x + threadIdx.x;
  long stride = (long)gridDim.x * blockDim.x;
  for (; i < n4; i += stride) {
    float4v v = reinterpret_cast<const float4v*>(in)[i];
    ushort4v o;
    o.x = f2bf(v.x); o.y = f2bf(v.y); o.z = f2bf(v.z); o.w = f2bf(v.w);
    reinterpret_cast<ushort4v*>(out)[i] = o;
  }
}

// ---------------- bf16 GEMM, C[M][N] = A[M][K] * B[N][K]^T ----------------
// m97 structure: 128x128 tile, BK=64, 256 threads (4 waves, 2x2), 16x16x32 MFMA,
// global_load_lds width-16 staging into linear LDS.
#define BM 128
#define BN 128
#define BK 64

__global__ __launch_bounds__(256) void gemm_bt(const unsigned short* __restrict__ A,
                                               const unsigned short* __restrict__ B,
                                               unsigned short* __restrict__ C,
                                               int M, int N, int K) {
  __shared__ unsigned short As[BM * BK];   // 16 KB
  __shared__ unsigned short Bs[BN * BK];   // 16 KB
  const int t = threadIdx.x;
  const int w = t >> 6;
  const int lane = t & 63;
  const int wm = w >> 1, wn = w & 1;       // 2x2 wave grid, each wave 64x64
  const int bm = blockIdx.x, bn = blockIdx.y;

  f32x4 acc[4][4] = {};

  const int lr = lane & 15;
  const int lk = (lane >> 4) * 8;

  for (int k0 = 0; k0 < K; k0 += BK) {
#pragma unroll
    for (int j = 0; j < 4; ++j) {
      int e = (t + j * 256) * 8;           // element index in 128x64 tile
      int row = e >> 6;
      int col = e & 63;
      const unsigned short* ga = A + (size_t)(bm * BM + row) * K + k0 + col;
      const unsigned short* gb = B + (size_t)(bn * BN + row) * K + k0 + col;
      unsigned short* la = As + (size_t)(w * 64 + j * 256) * 8;  // wave-uniform base
      unsigned short* lb = Bs + (size_t)(w * 64 + j * 256) * 8;
      __builtin_amdgcn_global_load_lds((const __attribute__((address_space(1))) void*)ga,
                                       (__attribute__((address_space(3))) void*)la, 16, 0, 0);
      __builtin_amdgcn_global_load_lds((const __attribute__((address_space(1))) void*)gb,
                                       (__attribute__((address_space(3))) void*)lb, 16, 0, 0);
    }
    __syncthreads();
#pragma unroll
    for (int ks = 0; ks < 2; ++ks) {
      bf16x8 af[4], bfr[4];
#pragma unroll
      for (int f = 0; f < 4; ++f) {
        af[f]  = *reinterpret_cast<const bf16x8*>(As + (size_t)(wm * 64 + f * 16 + lr) * BK + ks * 32 + lk);
        bfr[f] = *reinterpret_cast<const bf16x8*>(Bs + (size_t)(wn * 64 + f * 16 + lr) * BK + ks * 32 + lk);
      }
#pragma unroll
      for (int fm = 0; fm < 4; ++fm)
#pragma unroll
        for (int fn = 0; fn < 4; ++fn)
          acc[fm][fn] = __builtin_amdgcn_mfma_f32_16x16x32_bf16(af[fm], bfr[fn], acc[fm][fn], 0, 0, 0);
    }
    __syncthreads();
  }

  // epilogue: C/D layout col=lane&15, row=(lane>>4)*4+j  (m89-verified)
  const int cr = (lane >> 4) * 4;
  const int cc = lane & 15;
#pragma unroll
  for (int fm = 0; fm < 4; ++fm)
#pragma unroll
    for (int fn = 0; fn < 4; ++fn)
#pragma unroll
      for (int j = 0; j < 4; ++j) {
        int r = bm * BM + wm * 64 + fm * 16 + cr + j;
        int c = bn * BN + wn * 64 + fn * 16 + cc;
        C[(size_t)r * N + c] = f2bf(acc[fm][fn][j]);
      }
}

// ---------------- per-token log-sum-exp over V=32000 ----------------
__global__ __launch_bounds__(256) void row_lse(const unsigned short* __restrict__ sL,
                                               const unsigned short* __restrict__ tL,
                                               float* __restrict__ lse) {
  const int b = blockIdx.x;
  const unsigned short* row = (blockIdx.y == 0 ? sL : tL) + (size_t)b * VOC;
  __shared__ float red[4];
  __shared__ float bcast;

  float m = -3.0e38f;
  for (int i = threadIdx.x * 8; i < VOC; i += 2048) {
    ushort8 v = *reinterpret_cast<const ushort8*>(row + i);
#pragma unroll
    for (int j = 0; j < 8; ++j) m = fmaxf(m, bf2f(v[j]));
  }
#pragma unroll
  for (int o = 32; o > 0; o >>= 1) m = fmaxf(m, __shfl_xor(m, o));
  if ((threadIdx.x & 63) == 0) red[threadIdx.x >> 6] = m;
  __syncthreads();
  if (threadIdx.x == 0) bcast = fmaxf(fmaxf(red[0], red[1]), fmaxf(red[2], red[3]));
  __syncthreads();
  m = bcast;

  float s = 0.f;
  for (int i = threadIdx.x * 8; i < VOC; i += 2048) {
    ushort8 v = *reinterpret_cast<const ushort8*>(row + i);
#pragma unroll
    for (int j = 0; j < 8; ++j) s += __expf(bf2f(v[j]) - m);
  }
#pragma unroll
  for (int o = 32; o > 0; o >>= 1) s += __shfl_xor(s, o);
  __syncthreads();
  if ((threadIdx.x & 63) == 0) red[threadIdx.x >> 6] = s;
  __syncthreads();
  if (threadIdx.x == 0) lse[blockIdx.y * NTOK + b] = m + __logf(red[0] + red[1] + red[2] + red[3]);
}

// ---------------- per-token JSD ----------------
__global__ __launch_bounds__(256) void jsd_kernel(const unsigned short* __restrict__ sL,
                                                  const unsigned short* __restrict__ tL,
                                                  const float* __restrict__ lse,
                                                  const int* __restrict__ target,
                                                  float* __restrict__ acc_cnt) {
  const int b = blockIdx.x;
  const float lses = lse[b];
  const float lset = lse[NTOK + b];
  const unsigned short* srow = sL + (size_t)b * VOC;
  const unsigned short* trow = tL + (size_t)b * VOC;
  __shared__ float red[4];

  float local = 0.f;
  for (int i = threadIdx.x * 8; i < VOC; i += 2048) {
    ushort8 sv = *reinterpret_cast<const ushort8*>(srow + i);
    ushort8 tv = *reinterpret_cast<const ushort8*>(trow + i);
#pragma unroll
    for (int j = 0; j < 8; ++j) {
      float X = bf2f(sv[j]) - lses;     // log Q_i
      float Y = bf2f(tv[j]) - lset;     // log P_i
      float Q = __expf(X);
      float P = __expf(Y);
      float Mv = 0.5f * (P + Q);
      float lM = __logf(Mv);
      local += 0.5f * (P * (Y - lM) + Q * (X - lM));
    }
  }
#pragma unroll
  for (int o = 32; o > 0; o >>= 1) local += __shfl_xor(local, o);
  if ((threadIdx.x & 63) == 0) red[threadIdx.x >> 6] = local;
  __syncthreads();
  if (threadIdx.x == 0) {
    float tok = red[0] + red[1] + red[2] + red[3];
    if (target[b] != -100) {
      atomicAdd(&acc_cnt[0], tok);
      atomicAdd(&acc_cnt[1], 1.0f);
    }
  }
}

__global__ void finalize(const float* __restrict__ acc_cnt, float* __restrict__ out) {
  out[0] = acc_cnt[0] / fmaxf(acc_cnt[1], 1.0f);
}

// ---------------- launch ----------------
extern "C" void kernel_launch(void* const* d_in, const int* in_sizes, int n_in,
                              void* d_out, int out_size, void* d_ws, size_t ws_size,
                              hipStream_t stream) {
  const float* sIn = (const float*)d_in[0];   // [2048, 2048]
  const float* sW  = (const float*)d_in[1];   // [32000, 2048]
  const float* tIn = (const float*)d_in[2];   // [2048, 4096]
  const float* tW  = (const float*)d_in[3];   // [32000, 4096]
  const int*   tgt = (const int*)d_in[4];     // [2048]
  float* out = (float*)d_out;

  char* ws = (char*)d_ws;
  // workspace layout (~680.5 MB)
  unsigned short* bsW  = (unsigned short*)(ws + 0);            // 32000x2048 bf16
  unsigned short* btW  = (unsigned short*)(ws + 131072000);    // 32000x4096 bf16
  unsigned short* bsIn = (unsigned short*)(ws + 393216000);    // 2048x2048 bf16
  unsigned short* btIn = (unsigned short*)(ws + 401604608);    // 2048x4096 bf16
  unsigned short* sL   = (unsigned short*)(ws + 418381824);    // 2048x32000 bf16
  unsigned short* tL   = (unsigned short*)(ws + 549453824);    // 2048x32000 bf16
  float* lse           = (float*)(ws + 680525824);             // [2][2048]
  float* acc           = (float*)(ws + 680542208);             // [sum, cnt]

  hipMemsetAsync(acc, 0, 8, stream);

  cvt_f32_bf16<<<2048, 256, 0, stream>>>(sW,  bsW,  65536000L / 4);
  cvt_f32_bf16<<<2048, 256, 0, stream>>>(tW,  btW,  131072000L / 4);
  cvt_f32_bf16<<<1024, 256, 0, stream>>>(sIn, bsIn, 4194304L / 4);
  cvt_f32_bf16<<<1024, 256, 0, stream>>>(tIn, btIn, 8388608L / 4);

  gemm_bt<<<dim3(NTOK / BM, VOC / BN), 256, 0, stream>>>(bsIn, bsW, sL, NTOK, VOC, 2048);
  gemm_bt<<<dim3(NTOK / BM, VOC / BN), 256, 0, stream>>>(btIn, btW, tL, NTOK, VOC, 4096);

  row_lse<<<dim3(NTOK, 2), 256, 0, stream>>>(sL, tL, lse);
  jsd_kernel<<<NTOK, 256, 0, stream>>>(sL, tL, lse, tgt, acc);
  finalize<<<1, 1, 0, stream>>>(acc, out);
}